// Round 1
// baseline (137.900 us; speedup 1.0000x reference)
//
#include <hip/hip_runtime.h>

// Problem dims (fixed by reference setup_inputs)
#define BDIM 256
#define IDIM 1024
#define ODIM 1024

#define TILE_O 64   // outputs per block (one per lane)
#define TILE_B 8    // batches per block (2 per thread: ty, ty+4)
#define CH 128      // i-chunk staged in LDS per barrier

typedef float v2f __attribute__((ext_vector_type(2)));

__global__ __launch_bounds__(256, 2)
void softmax_t_linear_kernel(const float* __restrict__ x,
                             const float* __restrict__ w,
                             const float* __restrict__ bias,
                             float* __restrict__ out) {
  // xs: prescaled x slab for this block's 8 batch rows (32 KB)
  // ws: one i-chunk of w columns (32 KB)
  __shared__ float xs[TILE_B][IDIM];
  __shared__ float ws[CH][TILE_O];

  const int tx = threadIdx.x;            // 0..63 -> output column (lane)
  const int ty = threadIdx.y;            // 0..3  -> batch sub-row (wave id)
  const int tid = ty * 64 + tx;          // 0..255
  const int o0 = blockIdx.x * TILE_O;
  const int b0 = blockIdx.y * TILE_B;

  const float LOG2E = 1.4426950408889634f;  // also folds in 1/TEMPERATURE

  // ---- Stage x slab [TILE_B][IDIM], prescaled by log2e ----
  {
    const float4* xg = (const float4*)(x + (size_t)b0 * IDIM);
    float4* xl = (float4*)(&xs[0][0]);
    // TILE_B*IDIM/4 = 2048 float4s; 8 per thread, coalesced
#pragma unroll
    for (int k = 0; k < 8; ++k) {
      float4 v = xg[tid + k * 256];
      v.x *= LOG2E; v.y *= LOG2E; v.z *= LOG2E; v.w *= LOG2E;
      xl[tid + k * 256] = v;
    }
  }

  v2f num = {0.0f, 0.0f};
  v2f den = {0.0f, 0.0f};

  for (int i0 = 0; i0 < IDIM; i0 += CH) {
    __syncthreads();
    // ---- Stage w chunk [CH][TILE_O] ----
    {
      // CH*TILE_O/4 = 2048 float4s; 8 per thread
#pragma unroll
      for (int k = 0; k < 8; ++k) {
        int f = tid + k * 256;
        int row = f >> 4;        // 16 float4 per row of 64 floats
        int col = f & 15;
        float4 v = *(const float4*)(w + (size_t)(i0 + row) * ODIM + o0 + col * 4);
        *(float4*)(&ws[row][col * 4]) = v;
      }
    }
    __syncthreads();

    // ---- Inner reduction over this chunk ----
#pragma unroll 8
    for (int j = 0; j < CH; ++j) {
      float wv = ws[j][tx];              // stride-1 across lanes: conflict-free
      float xa = xs[ty][i0 + j];         // broadcast (same addr across wave)
      float xb = xs[ty + 4][i0 + j];     // broadcast
      v2f p = {xa * wv, xb * wv};        // p = log2e * z
      v2f t;
      t.x = exp2f(__builtin_fabsf(p.x)); // v_exp_f32 with |.| modifier
      t.y = exp2f(__builtin_fabsf(p.y));
      num += p * t;                      // hint v_pk_fma_f32
      den += t;
    }
  }

  // out = n * ln2 * (sum p*t) / (sum t) + bias   [p = log2e*z undone by ln2]
  const float LN2 = 0.6931471805599453f;
  const float scale = (float)IDIM * LN2;
  const int o = o0 + tx;
  const int b1 = b0 + ty;
  const int b2 = b0 + ty + 4;
  const float bo = bias[o];
  out[(size_t)b1 * ODIM + o] = scale * num.x / den.x + bo;
  out[(size_t)b2 * ODIM + o] = scale * num.y / den.y + bo;
}

extern "C" void kernel_launch(void* const* d_in, const int* in_sizes, int n_in,
                              void* d_out, int out_size, void* d_ws, size_t ws_size,
                              hipStream_t stream) {
  const float* x = (const float*)d_in[0];    // [256,1024] f32
  const float* w = (const float*)d_in[1];    // [1024,1024] f32
  const float* b = (const float*)d_in[2];    // [1024] f32
  float* out = (float*)d_out;                // [256,1024] f32

  dim3 grid(ODIM / TILE_O, BDIM / TILE_B);   // (16, 32) = 512 blocks
  dim3 block(64, 4);
  softmax_t_linear_kernel<<<grid, block, 0, stream>>>(x, w, b, out);
}

// Round 2
// 112.776 us; speedup vs baseline: 1.2228x; 1.2228x over previous
//
#include <hip/hip_runtime.h>

// Problem dims (fixed by reference setup_inputs)
#define BDIM 256
#define IDIM 1024
#define ODIM 1024

#define TILE_O 64   // outputs per block (one per lane)
#define TILE_B 8    // batches per block (2 per thread: ty, ty+4)
#define CH 128      // i-chunk staged in LDS per barrier

typedef float v2f __attribute__((ext_vector_type(2)));

#if __has_builtin(__builtin_amdgcn_exp2f)
#define FAST_EXP2(v) __builtin_amdgcn_exp2f(v)
#else
#define FAST_EXP2(v) exp2f(v)
#endif

__global__ __launch_bounds__(256, 2)
void softmax_t_linear_kernel(const float* __restrict__ x,
                             const float* __restrict__ w,
                             const float* __restrict__ bias,
                             float* __restrict__ out) {
  // xs: prescaled x slab for this block's 8 batch rows (32 KB)
  // ws: one i-chunk of w columns (32 KB)
  __shared__ float xs[TILE_B][IDIM];
  __shared__ float ws[CH][TILE_O];

  const int tx = threadIdx.x;            // 0..63 -> output column (lane)
  const int ty = threadIdx.y;            // 0..3  -> batch sub-row (wave id)
  const int tid = ty * 64 + tx;          // 0..255
  const int o0 = blockIdx.x * TILE_O;
  const int b0 = blockIdx.y * TILE_B;

  const float LOG2E = 1.4426950408889634f;  // also folds in 1/TEMPERATURE

  // ---- Stage x slab [TILE_B][IDIM], prescaled by log2e ----
  {
    const float4* xg = (const float4*)(x + (size_t)b0 * IDIM);
    float4* xl = (float4*)(&xs[0][0]);
    // TILE_B*IDIM/4 = 2048 float4s; 8 per thread, coalesced
#pragma unroll
    for (int k = 0; k < 8; ++k) {
      float4 v = xg[tid + k * 256];
      v.x *= LOG2E; v.y *= LOG2E; v.z *= LOG2E; v.w *= LOG2E;
      xl[tid + k * 256] = v;
    }
  }

  v2f num = {0.0f, 0.0f};
  v2f den = {0.0f, 0.0f};

  for (int i0 = 0; i0 < IDIM; i0 += CH) {
    __syncthreads();
    // ---- Stage w chunk [CH][TILE_O] ----
    {
      // CH*TILE_O/4 = 2048 float4s; 8 per thread
#pragma unroll
      for (int k = 0; k < 8; ++k) {
        int f = tid + k * 256;
        int row = f >> 4;        // 16 float4 per row of 64 floats
        int col = f & 15;
        float4 v = *(const float4*)(w + (size_t)(i0 + row) * ODIM + o0 + col * 4);
        *(float4*)(&ws[row][col * 4]) = v;
      }
    }
    __syncthreads();

    // ---- Inner reduction over this chunk ----
    // 4-j groups: x via broadcast ds_read_b128 (1 per row per 4j),
    // w via per-j b32 reads (adjacent j are 64 dwords apart -> ds_read2_b32).
    for (int j = 0; j < CH; j += 4) {
      float4 xa4 = *(const float4*)(&xs[ty][i0 + j]);       // broadcast 16B
      float4 xb4 = *(const float4*)(&xs[ty + 4][i0 + j]);   // broadcast 16B
      const float xa[4] = {xa4.x, xa4.y, xa4.z, xa4.w};
      const float xb[4] = {xb4.x, xb4.y, xb4.z, xb4.w};
#pragma unroll
      for (int u = 0; u < 4; ++u) {
        float wv = ws[j + u][tx];          // stride-1 lanes: conflict-free
        v2f p = {xa[u] * wv, xb[u] * wv};  // p = log2e * z
        v2f t;
        t.x = FAST_EXP2(__builtin_fabsf(p.x)); // single v_exp_f32, abs folded
        t.y = FAST_EXP2(__builtin_fabsf(p.y));
        num += p * t;
        den += t;
      }
    }
  }

  // out = n * ln2 * (sum p*t) / (sum t) + bias   [p = log2e*z undone by ln2]
  const float LN2 = 0.6931471805599453f;
  const float scale = (float)IDIM * LN2;
  const int o = o0 + tx;
  const int b1 = b0 + ty;
  const int b2 = b0 + ty + 4;
  const float bo = bias[o];
  out[(size_t)b1 * ODIM + o] = scale * num.x / den.x + bo;
  out[(size_t)b2 * ODIM + o] = scale * num.y / den.y + bo;
}

extern "C" void kernel_launch(void* const* d_in, const int* in_sizes, int n_in,
                              void* d_out, int out_size, void* d_ws, size_t ws_size,
                              hipStream_t stream) {
  const float* x = (const float*)d_in[0];    // [256,1024] f32
  const float* w = (const float*)d_in[1];    // [1024,1024] f32
  const float* b = (const float*)d_in[2];    // [1024] f32
  float* out = (float*)d_out;                // [256,1024] f32

  dim3 grid(ODIM / TILE_O, BDIM / TILE_B);   // (16, 32) = 512 blocks
  dim3 block(64, 4);
  softmax_t_linear_kernel<<<grid, block, 0, stream>>>(x, w, b, out);
}

// Round 3
// 105.274 us; speedup vs baseline: 1.3099x; 1.0713x over previous
//
#include <hip/hip_runtime.h>

// Problem dims (fixed by reference setup_inputs)
#define BDIM 256
#define IDIM 1024
#define ODIM 1024

#define TILE_O 64   // outputs per block (one per lane)
#define TILE_B 4    // batches per block (one per wave / ty)
#define CH 128      // i-chunk staged in LDS per barrier

typedef float v2f __attribute__((ext_vector_type(2)));

#if __has_builtin(__builtin_amdgcn_exp2f)
#define FAST_EXP2(v) __builtin_amdgcn_exp2f(v)
#else
#define FAST_EXP2(v) exp2f(v)
#endif

__global__ __launch_bounds__(256, 4)
void softmax_t_linear_kernel(const float* __restrict__ x,
                             const float* __restrict__ w,
                             const float* __restrict__ bias,
                             float* __restrict__ out) {
  // Only w is staged in LDS: 128 x 64 floats = 32 KB -> 4 blocks/CU.
  __shared__ float ws[CH][TILE_O];

  const int tx = threadIdx.x;            // 0..63 -> output column (lane)
  const int ty = threadIdx.y;            // 0..3  -> batch row (one wave each)
  const int tid = ty * 64 + tx;          // 0..255
  const int o0 = blockIdx.x * TILE_O;
  const int b0 = blockIdx.y * TILE_B;

  const float LOG2E = 1.4426950408889634f;  // folds 1/TEMPERATURE too

  // x row for this wave: all lanes read the same (uniform) address ->
  // compiler can scalarize to s_load; x is NOT prescaled (LOG2E goes into w).
  const float* xrow = x + (size_t)(b0 + ty) * IDIM;

  // Packed accumulators over j-parity: .x = even j, .y = odd j.
  v2f num = {0.0f, 0.0f};
  v2f den = {0.0f, 0.0f};

  for (int i0 = 0; i0 < IDIM; i0 += CH) {
    __syncthreads();
    // ---- Stage w chunk [CH][TILE_O], scaled by LOG2E ----
    // CH*TILE_O/4 = 2048 float4s; 8 per thread, coalesced global reads.
#pragma unroll
    for (int k = 0; k < 8; ++k) {
      int f = tid + k * 256;
      int row = f >> 4;        // 16 float4 per 64-float row
      int col = f & 15;
      float4 v = *(const float4*)(w + (size_t)(i0 + row) * ODIM + o0 + col * 4);
      v.x *= LOG2E; v.y *= LOG2E; v.z *= LOG2E; v.w *= LOG2E;
      *(float4*)(&ws[row][col * 4]) = v;
    }
    __syncthreads();

    // ---- Inner reduction: 8 j per iteration ----
#pragma unroll 4
    for (int j = 0; j < CH; j += 8) {
      // uniform x loads (16B each) -> s_load_dwordx4 expected
      float4 xq0 = *(const float4*)(xrow + i0 + j);
      float4 xq1 = *(const float4*)(xrow + i0 + j + 4);
      float wv[8];
#pragma unroll
      for (int u = 0; u < 8; ++u) wv[u] = ws[j + u][tx];  // stride-1 lanes; adjacent
                                                          // u merge to ds_read2_b32
      v2f p0 = {xq0.x * wv[0], xq0.y * wv[1]};   // p = log2e * z
      v2f p1 = {xq0.z * wv[2], xq0.w * wv[3]};
      v2f p2 = {xq1.x * wv[4], xq1.y * wv[5]};
      v2f p3 = {xq1.z * wv[6], xq1.w * wv[7]};
      v2f t0, t1, t2, t3;
      t0.x = FAST_EXP2(__builtin_fabsf(p0.x));
      t0.y = FAST_EXP2(__builtin_fabsf(p0.y));
      t1.x = FAST_EXP2(__builtin_fabsf(p1.x));
      t1.y = FAST_EXP2(__builtin_fabsf(p1.y));
      t2.x = FAST_EXP2(__builtin_fabsf(p2.x));
      t2.y = FAST_EXP2(__builtin_fabsf(p2.y));
      t3.x = FAST_EXP2(__builtin_fabsf(p3.x));
      t3.y = FAST_EXP2(__builtin_fabsf(p3.y));
      num += p0 * t0; den += t0;   // v_pk_fma_f32 / v_pk_add_f32
      num += p1 * t1; den += t1;
      num += p2 * t2; den += t2;
      num += p3 * t3; den += t3;
    }
  }

  // out = n * ln2 * (sum p*t) / (sum t) + bias   [p = log2e*z undone by ln2]
  const float LN2 = 0.6931471805599453f;
  const float scale = (float)IDIM * LN2;
  const float numv = num.x + num.y;
  const float denv = den.x + den.y;
  const int o = o0 + tx;
  out[(size_t)(b0 + ty) * ODIM + o] = scale * numv / denv + bias[o];
}

extern "C" void kernel_launch(void* const* d_in, const int* in_sizes, int n_in,
                              void* d_out, int out_size, void* d_ws, size_t ws_size,
                              hipStream_t stream) {
  const float* x = (const float*)d_in[0];    // [256,1024] f32
  const float* w = (const float*)d_in[1];    // [1024,1024] f32
  const float* b = (const float*)d_in[2];    // [1024] f32
  float* out = (float*)d_out;                // [256,1024] f32

  dim3 grid(ODIM / TILE_O, BDIM / TILE_B);   // (16, 64) = 1024 blocks = 4/CU
  dim3 block(64, 4);
  softmax_t_linear_kernel<<<grid, block, 0, stream>>>(x, w, b, out);
}

// Round 4
// 103.088 us; speedup vs baseline: 1.3377x; 1.0212x over previous
//
#include <hip/hip_runtime.h>

// Problem dims (fixed by reference setup_inputs)
#define BDIM 256
#define IDIM 1024
#define ODIM 1024

#define TILE_O 64   // outputs per block (one per lane)
#define TILE_B 4    // batches per block (one per wave / ty)
#define CH 64       // i-chunk staged in LDS per barrier (16KB w + 1KB x -> 8 blocks/CU)

typedef float v2f __attribute__((ext_vector_type(2)));

#if __has_builtin(__builtin_amdgcn_exp2f)
#define FAST_EXP2(v) __builtin_amdgcn_exp2f(v)
#else
#define FAST_EXP2(v) exp2f(v)
#endif

__global__ __launch_bounds__(256, 8)
void softmax_t_linear_kernel(const float* __restrict__ x,
                             const float* __restrict__ w,
                             const float* __restrict__ bias,
                             float* __restrict__ out) {
  __shared__ float ws[CH][TILE_O];   // 16 KB: w chunk
  __shared__ float xs[TILE_B][CH];   // 1 KB: x chunk, prescaled by log2e

  const int tx = threadIdx.x;            // 0..63 -> output column (lane)
  const int ty = threadIdx.y;            // 0..3  -> batch row (one wave each)
  const int tid = ty * 64 + tx;          // 0..255
  const int o0 = blockIdx.x * TILE_O;
  const int b0 = blockIdx.y * TILE_B;

  const float LOG2E = 1.4426950408889634f;  // folds 1/TEMPERATURE too
  const float* xrow = x + (size_t)(b0 + ty) * IDIM;

  // Packed accumulators over i-parity: .x = even i, .y = odd i.
  v2f num = {0.0f, 0.0f};
  v2f den = {0.0f, 0.0f};

  for (int i0 = 0; i0 < IDIM; i0 += CH) {
    __syncthreads();
    // ---- Stage x chunk: each wave stages its own row (16 float4s) ----
    if (tx < CH / 4) {
      float4 v = *(const float4*)(xrow + i0 + tx * 4);
      v.x *= LOG2E; v.y *= LOG2E; v.z *= LOG2E; v.w *= LOG2E;
      *(float4*)(&xs[ty][tx * 4]) = v;
    }
    // ---- Stage w chunk [CH][TILE_O] (pure copy; scale lives in x) ----
    // CH*TILE_O/4 = 1024 float4s; 4 per thread, coalesced.
#pragma unroll
    for (int k = 0; k < 4; ++k) {
      int f = tid + k * 256;
      int row = f >> 4;        // 16 float4 per 64-float row
      int col = f & 15;
      *(float4*)(&ws[row][col * 4]) =
          *(const float4*)(w + (size_t)(i0 + row) * ODIM + o0 + col * 4);
    }
    __syncthreads();

    // ---- Inner reduction: 8 i per iteration ----
#pragma unroll 4
    for (int j = 0; j < CH; j += 8) {
      float4 xq0 = *(const float4*)(&xs[ty][j]);       // broadcast ds_read_b128
      float4 xq1 = *(const float4*)(&xs[ty][j + 4]);   // broadcast ds_read_b128
      float wv[8];
#pragma unroll
      for (int u = 0; u < 8; ++u) wv[u] = ws[j + u][tx];  // pairs -> ds_read2_b32
      v2f p0 = {xq0.x * wv[0], xq0.y * wv[1]};   // p = log2e * z
      v2f p1 = {xq0.z * wv[2], xq0.w * wv[3]};
      v2f p2 = {xq1.x * wv[4], xq1.y * wv[5]};
      v2f p3 = {xq1.z * wv[6], xq1.w * wv[7]};
      v2f t0, t1, t2, t3;
      t0.x = FAST_EXP2(__builtin_fabsf(p0.x));
      t0.y = FAST_EXP2(__builtin_fabsf(p0.y));
      t1.x = FAST_EXP2(__builtin_fabsf(p1.x));
      t1.y = FAST_EXP2(__builtin_fabsf(p1.y));
      t2.x = FAST_EXP2(__builtin_fabsf(p2.x));
      t2.y = FAST_EXP2(__builtin_fabsf(p2.y));
      t3.x = FAST_EXP2(__builtin_fabsf(p3.x));
      t3.y = FAST_EXP2(__builtin_fabsf(p3.y));
      num += p0 * t0; den += t0;   // v_pk_fma_f32 / v_pk_add_f32
      num += p1 * t1; den += t1;
      num += p2 * t2; den += t2;
      num += p3 * t3; den += t3;
    }
  }

  // out = n * ln2 * (sum p*t) / (sum t) + bias   [p = log2e*z undone by ln2]
  const float LN2 = 0.6931471805599453f;
  const float scale = (float)IDIM * LN2;
  const float numv = num.x + num.y;
  const float denv = den.x + den.y;
  const int o = o0 + tx;
  out[(size_t)(b0 + ty) * ODIM + o] = scale * numv / denv + bias[o];
}

extern "C" void kernel_launch(void* const* d_in, const int* in_sizes, int n_in,
                              void* d_out, int out_size, void* d_ws, size_t ws_size,
                              hipStream_t stream) {
  const float* x = (const float*)d_in[0];    // [256,1024] f32
  const float* w = (const float*)d_in[1];    // [1024,1024] f32
  const float* b = (const float*)d_in[2];    // [1024] f32
  float* out = (float*)d_out;                // [256,1024] f32

  dim3 grid(ODIM / TILE_O, BDIM / TILE_B);   // (16, 64) = 1024 blocks = 8/CU... 4 resident waves/SIMD x 2 passes
  dim3 block(64, 4);
  softmax_t_linear_kernel<<<grid, block, 0, stream>>>(x, w, b, out);
}